// Round 1
// 164.696 us; speedup vs baseline: 1.0231x; 1.0231x over previous
//
#include <hip/hip_runtime.h>
#include <hip/hip_bf16.h>

// MoLoRA = base linear + top-2 routed LoRA.
//   Abuf[T,2176] = [ bf16(x) | bf16(alpha*cw*(x@A2^T)) ]      (A2 = A_w as [128,2048])
//   Bfull[O,2176] = [ bf16(W) | bf16(B2^T) ]   (B2[e*16+r,o]=B_w[e,o,r])
//   out[T,O] = Abuf @ Bfull^T     -- single bf16 MFMA GEMM, K=2176
// T=4096, H=2048, O=2048, E=8, R=16, Kaug=2176.
//
// R1: XOR k-chunk LDS swizzle -> SQ_LDS_BANK_CONFLICT 1.34e7 -> 0.
// R2: (a) main GEMM 128x64 tiles, 2-wave blocks, grid 1024; (b) fused router.
// R3: GEMM rebuilt as deep-pipelined 256x128 tile, 8 waves (4Mx2N, 64x64/wave):
//     - 3-deep LDS buffer rotation (144 KB), stage tile kt+2 while computing kt
//     - counted s_waitcnt vmcnt(6) (never 0 in steady state) + raw s_barrier
//       so the 6 global_load_lds of the next tile stay in flight across barriers
//     - s_setprio(1) around MFMA clusters; XCD-chunked block swizzle (256%8==0)
//     - same verified XOR k-chunk swizzle / fragment addressing, scaled up.

typedef __bf16 bf16x8 __attribute__((ext_vector_type(8)));
typedef float f32x4 __attribute__((ext_vector_type(4)));

__device__ __forceinline__ __bf16 f2bf(float f) {
  union { float f; unsigned u; } v; v.f = f;
  unsigned r = (v.u + 0x7FFFu + ((v.u >> 16) & 1u)) >> 16;  // RNE
  unsigned short s = (unsigned short)r;
  return __builtin_bit_cast(__bf16, s);
}

__device__ __forceinline__ void ld_lds16(const void* g, void* l) {
  __builtin_amdgcn_global_load_lds((__attribute__((address_space(1))) void*)g,
                                   (__attribute__((address_space(3))) void*)l,
                                   16, 0, 0);
}

// ---------------- fused prep: W->Bfull[:,0:2048], A_w->A2, B_w->Bfull[:,2048:] ----
__global__ void prep_kernel(const float* __restrict__ W, const float* __restrict__ Aw,
                            const float* __restrict__ Bw, __bf16* __restrict__ Bfull,
                            __bf16* __restrict__ A2) {
  const int b = blockIdx.x, tid = threadIdx.x;
  if (b < 2176) {
    const float* src = (b < 2048) ? (W + (size_t)b * 2048)
                                  : (Aw + (size_t)(b - 2048) * 2048);
    __bf16* dst = (b < 2048) ? (Bfull + (size_t)b * 2176)
                             : (A2 + (size_t)(b - 2048) * 2048);
    const int c = tid * 8;
    float4 a = *(const float4*)(src + c);
    float4 d = *(const float4*)(src + c + 4);
    bf16x8 v;
    v[0] = f2bf(a.x); v[1] = f2bf(a.y); v[2] = f2bf(a.z); v[3] = f2bf(a.w);
    v[4] = f2bf(d.x); v[5] = f2bf(d.y); v[6] = f2bf(d.z); v[7] = f2bf(d.w);
    *(bf16x8*)(dst + c) = v;
  } else {
    // pack B_w [E,O,R] -> Bfull[o, 2048 + e*16 + r]
    const int idx = (b - 2176) * 256 + tid;  // 0..16383
    const int e = idx >> 11, o = idx & 2047;
    const float4* s = (const float4*)(Bw + ((size_t)e * 2048 + o) * 16);
    float4 v0 = s[0], v1 = s[1], v2 = s[2], v3 = s[3];
    __bf16* d = Bfull + (size_t)o * 2176 + 2048 + e * 16;
    bf16x8 lo, hi;
    lo[0] = f2bf(v0.x); lo[1] = f2bf(v0.y); lo[2] = f2bf(v0.z); lo[3] = f2bf(v0.w);
    lo[4] = f2bf(v1.x); lo[5] = f2bf(v1.y); lo[6] = f2bf(v1.z); lo[7] = f2bf(v1.w);
    hi[0] = f2bf(v2.x); hi[1] = f2bf(v2.y); hi[2] = f2bf(v2.z); hi[3] = f2bf(v2.w);
    hi[4] = f2bf(v3.x); hi[5] = f2bf(v3.y); hi[6] = f2bf(v3.z); hi[7] = f2bf(v3.w);
    *(bf16x8*)d = lo;
    *(bf16x8*)(d + 8) = hi;
  }
}

// ---------------- fused router + LoRA-down (t2) ----------------
// 16 tokens/block, grid 256. Phases:
//  1. x -> bf16 -> Abuf[:,0:2048] + LDS xs (row pad +8 breaks bank aliasing)
//  2. fp32 logits (token=lane&15, slice=tid>>4), shuffle+LDS reduce, top-2 -> cws
//  3. t[16,128] = xs @ A2^T via MFMA (B-frags straight from L2-hot A2)
//  4. scale 16*cw, bf16, scatter into Abuf[:,2048:2176]
__global__ __launch_bounds__(256) void router_t2(
    const float* __restrict__ x, const float* __restrict__ gw,
    const __bf16* __restrict__ A2, __bf16* __restrict__ Abuf) {
  __shared__ __align__(16) __bf16 xs[16][2056];  // 64.25 KB, +8 pad
  __shared__ float red[4][16][8];
  __shared__ float cws[16][8];
  const int tid = threadIdx.x;
  const int wave = tid >> 6, lane = tid & 63;
  const int t0 = blockIdx.x * 16;

  // ---- phase 1: one token-row per iteration, fully coalesced ----
#pragma unroll 4
  for (int i = 0; i < 16; ++i) {
    const float* xr = x + (size_t)(t0 + i) * 2048 + tid * 8;
    float4 a = *(const float4*)xr;
    float4 b = *(const float4*)(xr + 4);
    bf16x8 v;
    v[0] = f2bf(a.x); v[1] = f2bf(a.y); v[2] = f2bf(a.z); v[3] = f2bf(a.w);
    v[4] = f2bf(b.x); v[5] = f2bf(b.y); v[6] = f2bf(b.z); v[7] = f2bf(b.w);
    *(bf16x8*)(Abuf + (size_t)(t0 + i) * 2176 + tid * 8) = v;
    *(bf16x8*)&xs[i][tid * 8] = v;
  }
  __syncthreads();

  // ---- phase 2: logits from bf16 x (error ~1e-3 of logit scale; top-2 stable) ----
  const int tok = tid & 15, slc = tid >> 4;
  const int c0 = slc * 128;
  float acc[8] = {0, 0, 0, 0, 0, 0, 0, 0};
  for (int j8 = 0; j8 < 16; ++j8) {
    bf16x8 xv = *(const bf16x8*)&xs[tok][c0 + j8 * 8];
    float xf[8];
#pragma unroll
    for (int j = 0; j < 8; ++j) xf[j] = (float)xv[j];
#pragma unroll
    for (int e = 0; e < 8; ++e) {
      float4 g0 = *(const float4*)(gw + e * 2048 + c0 + j8 * 8);
      float4 g1 = *(const float4*)(gw + e * 2048 + c0 + j8 * 8 + 4);
      acc[e] += xf[0] * g0.x + xf[1] * g0.y + xf[2] * g0.z + xf[3] * g0.w +
                xf[4] * g1.x + xf[5] * g1.y + xf[6] * g1.z + xf[7] * g1.w;
    }
  }
#pragma unroll
  for (int e = 0; e < 8; ++e) {
    acc[e] += __shfl_down(acc[e], 16);
    acc[e] += __shfl_down(acc[e], 32);
  }
  if (lane < 16) {
#pragma unroll
    for (int e = 0; e < 8; ++e) red[wave][lane][e] = acc[e];
  }
  __syncthreads();
  if (tid < 16) {
    float lg[8];
#pragma unroll
    for (int e = 0; e < 8; ++e)
      lg[e] = red[0][tid][e] + red[1][tid][e] + red[2][tid][e] + red[3][tid][e];
    int a = 0;
    for (int e = 1; e < 8; ++e) if (lg[e] > lg[a]) a = e;
    int b = (a == 0) ? 1 : 0;
    for (int e = 0; e < 8; ++e) if (e != a && lg[e] > lg[b]) b = e;
    const float d = __expf(lg[b] - lg[a]);
    float o[8] = {0, 0, 0, 0, 0, 0, 0, 0};
    o[a] = 1.0f / (1.0f + d);
    o[b] = d / (1.0f + d);
#pragma unroll
    for (int e = 0; e < 8; ++e) cws[tid][e] = o[e];
  }
  __syncthreads();

  // ---- phase 3: t = xs @ A2^T, wave handles experts nt0, nt0+1 ----
  const int m = lane & 15, q = lane >> 4;
  const int nt0 = wave * 2;
  f32x4 tacc[2] = {};
  for (int ks = 0; ks < 64; ++ks) {
    bf16x8 af = *(const bf16x8*)&xs[m][ks * 32 + q * 8];
#pragma unroll
    for (int h = 0; h < 2; ++h) {
      bf16x8 bfg = *(const bf16x8*)(A2 + (size_t)((nt0 + h) * 16 + m) * 2048 +
                                    ks * 32 + q * 8);
      tacc[h] = __builtin_amdgcn_mfma_f32_16x16x32_bf16(af, bfg, tacc[h], 0, 0, 0);
    }
  }
  // ---- phase 4: scale + store. C layout: col=lane&15, row=q*4+reg ----
#pragma unroll
  for (int h = 0; h < 2; ++h) {
    const int nt = nt0 + h;
#pragma unroll
    for (int rg = 0; rg < 4; ++rg) {
      const int trow = q * 4 + rg;
      const float s = tacc[h][rg] * 16.0f * cws[trow][nt];
      Abuf[(size_t)(t0 + trow) * 2176 + 2048 + nt * 16 + m] = f2bf(s);
    }
  }
}

// ---------------- deep-pipelined MFMA GEMM: C[m,n] = sum_k A[m,k]*B[n,k] ----------
// BM=256, BN=128, BK=64. 512 threads = 8 waves in 4(M)x2(N) grid, 64x64 per wave.
// 3 LDS buffers (48 KB each = A 32 chunks + B 16 chunks of [8 rows][64 k], XOR
// k-chunk swizzled exactly as R1). Pipeline: compute tile kt from buf kt%3 while
// tiles kt+1, kt+2 are staged/in flight; counted vmcnt(6) keeps the newest 6
// global_load_lds in flight across the barrier (T3+T4); setprio around MFMA (T5).
// Grid 16x16 = 256 blocks = 1 block/CU; XCD-chunked swizzle (bijective, 256%8==0).
__global__ __launch_bounds__(512, 2) void mfma_gemm_bt2(
    const __bf16* __restrict__ A, const __bf16* __restrict__ B,
    float* __restrict__ C, int lda, int ldb, int ldc, int kiters) {
  __shared__ __align__(16) __bf16 lds[3 * 24576];  // 144 KB
  const int tid = threadIdx.x;
  const int wave = tid >> 6;
  const int lane = tid & 63;

  // XCD-aware chunked swizzle: 256 wgs, 8 XCDs -> 32 consecutive swz ids per XCD
  // (all 16 M-tiles x 2 N-tiles: B panels L2-resident per XCD).
  const int wg = blockIdx.x + (blockIdx.y << 4);
  const int swz = (wg & 7) * 32 + (wg >> 3);
  const int tm = (swz & 15) * 256;
  const int tn = (swz >> 4) * 128;

  const int srow = lane >> 3;                 // row within 8-row staging chunk
  const int skoff = ((lane & 7) ^ srow) * 8;  // XOR-swizzled k offset (elems)

  const int wr = wave >> 1, wc = wave & 1;    // 4x2 wave grid
  const int rlo = lane & 7;
  const int rb3 = (lane >> 3) & 1;
  const int qb = lane >> 4;

  f32x4 acc[4][4] = {};

  // stage tile kt into buffer buf: 48 chunk-loads split over 8 waves (6/thread)
  auto stage = [&](int buf, int kt) {
    const int kc = kt * 64;
    __bf16* Ls = lds + buf * 24576;
#pragma unroll
    for (int r = 0; r < 4; ++r) {
      const int ch = wave + r * 8;  // A: 32 chunks of 8 rows
      ld_lds16(A + (size_t)(tm + ch * 8 + srow) * lda + kc + skoff, &Ls[ch * 512]);
    }
#pragma unroll
    for (int r = 0; r < 2; ++r) {
      const int ch = wave + r * 8;  // B: 16 chunks of 8 rows
      ld_lds16(B + (size_t)(tn + ch * 8 + srow) * ldb + kc + skoff,
               &Ls[16384 + ch * 512]);
    }
  };

  // prologue: tiles 0 and 1 in flight; wait for tile 0 (6 newest stay in flight)
  stage(0, 0);
  stage(1, 1);
  asm volatile("s_waitcnt vmcnt(6)" ::: "memory");
  __builtin_amdgcn_s_barrier();

  int cb = 0;
  for (int kt = 0; kt < kiters; ++kt) {
    const bool pf = (kt + 2 < kiters);
    if (pf) stage((kt + 2) % 3, kt + 2);  // overwrites buf read at iter kt-1 (safe)

    const __bf16* As = lds + cb * 24576;
    const __bf16* Bs = As + 16384;
#pragma unroll
    for (int ks = 0; ks < 2; ++ks) {
      bf16x8 af[4], bfg[4];
      const int q8 = ((ks * 4 + qb) ^ rlo) * 8;
#pragma unroll
      for (int i = 0; i < 4; ++i) {
        const int rh = wr * 8 + i * 2 + rb3;
        af[i] = *(const bf16x8*)&As[rh * 512 + rlo * 64 + q8];
      }
#pragma unroll
      for (int j = 0; j < 4; ++j) {
        const int rh = wc * 8 + j * 2 + rb3;
        bfg[j] = *(const bf16x8*)&Bs[rh * 512 + rlo * 64 + q8];
      }
      __builtin_amdgcn_s_setprio(1);
#pragma unroll
      for (int i = 0; i < 4; ++i)
#pragma unroll
        for (int j = 0; j < 4; ++j)
          acc[i][j] =
              __builtin_amdgcn_mfma_f32_16x16x32_bf16(af[i], bfg[j], acc[i][j], 0, 0, 0);
      __builtin_amdgcn_s_setprio(0);
    }
    // my ds_reads of buf cb done (next iter stages into it) ...
    asm volatile("s_waitcnt lgkmcnt(0)" ::: "memory");
    // ... and tile kt+1's 6 loads landed; tile kt+2's 6 remain in flight.
    if (pf) {
      asm volatile("s_waitcnt vmcnt(6)" ::: "memory");
    } else {
      asm volatile("s_waitcnt vmcnt(0)" ::: "memory");
    }
    __builtin_amdgcn_s_barrier();
    cb = (cb + 1 == 3) ? 0 : cb + 1;
  }

  // C/D layout: col = lane&15, row = (lane>>4)*4 + reg
  const int crow0 = tm + wr * 64 + (lane >> 4) * 4;
  const int ccol0 = tn + wc * 64 + (lane & 15);
#pragma unroll
  for (int i = 0; i < 4; ++i)
#pragma unroll
    for (int j = 0; j < 4; ++j)
#pragma unroll
      for (int rg = 0; rg < 4; ++rg)
        C[(size_t)(crow0 + i * 16 + rg) * ldc + ccol0 + j * 16] = acc[i][j][rg];
}

extern "C" void kernel_launch(void* const* d_in, const int* in_sizes, int n_in,
                              void* d_out, int out_size, void* d_ws, size_t ws_size,
                              hipStream_t stream) {
  const float* x = (const float*)d_in[0];       // [2,2048,2048] -> [4096,2048]
  const float* weight = (const float*)d_in[1];  // [2048,2048]
  const float* gate_w = (const float*)d_in[2];  // [8,2048]
  const float* A_w = (const float*)d_in[3];     // [8,16,2048] == [128,2048]
  const float* B_w = (const float*)d_in[4];     // [8,2048,16]
  float* out = (float*)d_out;                   // [4096,2048]

  char* ws = (char*)d_ws;
  __bf16* Abuf = (__bf16*)ws;                // [4096,2176] bf16 = 17,825,792 B
  __bf16* Bfull = (__bf16*)(ws + 17825792);  // [2048,2176] bf16 =  8,912,896 B
  __bf16* A2 = (__bf16*)(ws + 26738688);     // [128,2048]  bf16 =    524,288 B

  // 1. prep: W -> Bfull[:,0:2048]; A_w -> A2; B_w -> Bfull[:,2048:2176]
  prep_kernel<<<2240, 256, 0, stream>>>(weight, A_w, B_w, Bfull, A2);
  // 2. router + x->bf16 + LoRA-down (t2) into Abuf
  router_t2<<<256, 256, 0, stream>>>(x, gate_w, A2, Abuf);
  // 3. out = Abuf @ Bfull^T  (K=2176 fuses base + LoRA-up)
  mfma_gemm_bt2<<<dim3(16, 16), 512, 0, stream>>>(Abuf, Bfull, out, 2176, 2176,
                                                  2048, 34);
}

// Round 2
// 162.707 us; speedup vs baseline: 1.0357x; 1.0122x over previous
//
#include <hip/hip_runtime.h>
#include <hip/hip_bf16.h>

// MoLoRA = base linear + top-2 routed LoRA.
//   Abuf[T,2176] = [ bf16(x) | bf16(alpha*cw*(x@A2^T)) ]      (A2 = A_w as [128,2048])
//   Bfull[O,2176] = [ bf16(W) | bf16(B2^T) ]   (B2[e*16+r,o]=B_w[e,o,r])
//   out[T,O] = Abuf @ Bfull^T     -- single bf16 MFMA GEMM, K=2176
// T=4096, H=2048, O=2048, E=8, R=16, Kaug=2176.
//
// R1: XOR k-chunk LDS swizzle -> SQ_LDS_BANK_CONFLICT 1.34e7 -> 0.
// R2: 128x64 tiles / fused router (3 dispatches total).
// R3: 256x128 tile, 8 waves, 3-deep pipeline, counted vmcnt(6). 45.8us, Mfma 30%.
// R4: (a) ks-split: waves 0-3 / 4-7 each own a 128x64 output tile (2x2 over the
//         256x128 block) and accumulate only their K=32 half of each BK=64 tile
//         -> per-wave reuse 4x -> 5.33x (12 ds_read_b128 per 32 MFMAs), LDS need
//         drops 105 -> 79 B/cyc/CU at full MFMA rate; partials combined through
//         LDS in the epilogue (conflict-free 16B/lane layout).
//     (b) fine 2-phase-per-K-tile interleave (m201 template): per phase
//         {ds_read subtile + 3 staging gloads -> barrier -> lgkmcnt(0) ->
//          setprio(1) 16 MFMA setprio(0) -> barrier}; vmcnt(6) once per tile.
//     (c) XCD swizzle -> 4Mx8N rectangle per XCD (halves per-XCD footprint).

typedef __bf16 bf16x8 __attribute__((ext_vector_type(8)));
typedef float f32x4 __attribute__((ext_vector_type(4)));

__device__ __forceinline__ __bf16 f2bf(float f) {
  union { float f; unsigned u; } v; v.f = f;
  unsigned r = (v.u + 0x7FFFu + ((v.u >> 16) & 1u)) >> 16;  // RNE
  unsigned short s = (unsigned short)r;
  return __builtin_bit_cast(__bf16, s);
}

__device__ __forceinline__ void ld_lds16(const void* g, void* l) {
  __builtin_amdgcn_global_load_lds((__attribute__((address_space(1))) void*)g,
                                   (__attribute__((address_space(3))) void*)l,
                                   16, 0, 0);
}

// ---------------- fused prep: W->Bfull[:,0:2048], A_w->A2, B_w->Bfull[:,2048:] ----
__global__ void prep_kernel(const float* __restrict__ W, const float* __restrict__ Aw,
                            const float* __restrict__ Bw, __bf16* __restrict__ Bfull,
                            __bf16* __restrict__ A2) {
  const int b = blockIdx.x, tid = threadIdx.x;
  if (b < 2176) {
    const float* src = (b < 2048) ? (W + (size_t)b * 2048)
                                  : (Aw + (size_t)(b - 2048) * 2048);
    __bf16* dst = (b < 2048) ? (Bfull + (size_t)b * 2176)
                             : (A2 + (size_t)(b - 2048) * 2048);
    const int c = tid * 8;
    float4 a = *(const float4*)(src + c);
    float4 d = *(const float4*)(src + c + 4);
    bf16x8 v;
    v[0] = f2bf(a.x); v[1] = f2bf(a.y); v[2] = f2bf(a.z); v[3] = f2bf(a.w);
    v[4] = f2bf(d.x); v[5] = f2bf(d.y); v[6] = f2bf(d.z); v[7] = f2bf(d.w);
    *(bf16x8*)(dst + c) = v;
  } else {
    // pack B_w [E,O,R] -> Bfull[o, 2048 + e*16 + r]
    const int idx = (b - 2176) * 256 + tid;  // 0..16383
    const int e = idx >> 11, o = idx & 2047;
    const float4* s = (const float4*)(Bw + ((size_t)e * 2048 + o) * 16);
    float4 v0 = s[0], v1 = s[1], v2 = s[2], v3 = s[3];
    __bf16* d = Bfull + (size_t)o * 2176 + 2048 + e * 16;
    bf16x8 lo, hi;
    lo[0] = f2bf(v0.x); lo[1] = f2bf(v0.y); lo[2] = f2bf(v0.z); lo[3] = f2bf(v0.w);
    lo[4] = f2bf(v1.x); lo[5] = f2bf(v1.y); lo[6] = f2bf(v1.z); lo[7] = f2bf(v1.w);
    hi[0] = f2bf(v2.x); hi[1] = f2bf(v2.y); hi[2] = f2bf(v2.z); hi[3] = f2bf(v2.w);
    hi[4] = f2bf(v3.x); hi[5] = f2bf(v3.y); hi[6] = f2bf(v3.z); hi[7] = f2bf(v3.w);
    *(bf16x8*)d = lo;
    *(bf16x8*)(d + 8) = hi;
  }
}

// ---------------- fused router + LoRA-down (t2) ----------------
__global__ __launch_bounds__(256) void router_t2(
    const float* __restrict__ x, const float* __restrict__ gw,
    const __bf16* __restrict__ A2, __bf16* __restrict__ Abuf) {
  __shared__ __align__(16) __bf16 xs[16][2056];  // 64.25 KB, +8 pad
  __shared__ float red[4][16][8];
  __shared__ float cws[16][8];
  const int tid = threadIdx.x;
  const int wave = tid >> 6, lane = tid & 63;
  const int t0 = blockIdx.x * 16;

  // ---- phase 1: one token-row per iteration, fully coalesced ----
#pragma unroll 4
  for (int i = 0; i < 16; ++i) {
    const float* xr = x + (size_t)(t0 + i) * 2048 + tid * 8;
    float4 a = *(const float4*)xr;
    float4 b = *(const float4*)(xr + 4);
    bf16x8 v;
    v[0] = f2bf(a.x); v[1] = f2bf(a.y); v[2] = f2bf(a.z); v[3] = f2bf(a.w);
    v[4] = f2bf(b.x); v[5] = f2bf(b.y); v[6] = f2bf(b.z); v[7] = f2bf(b.w);
    *(bf16x8*)(Abuf + (size_t)(t0 + i) * 2176 + tid * 8) = v;
    *(bf16x8*)&xs[i][tid * 8] = v;
  }
  __syncthreads();

  // ---- phase 2: logits ----
  const int tok = tid & 15, slc = tid >> 4;
  const int c0 = slc * 128;
  float acc[8] = {0, 0, 0, 0, 0, 0, 0, 0};
  for (int j8 = 0; j8 < 16; ++j8) {
    bf16x8 xv = *(const bf16x8*)&xs[tok][c0 + j8 * 8];
    float xf[8];
#pragma unroll
    for (int j = 0; j < 8; ++j) xf[j] = (float)xv[j];
#pragma unroll
    for (int e = 0; e < 8; ++e) {
      float4 g0 = *(const float4*)(gw + e * 2048 + c0 + j8 * 8);
      float4 g1 = *(const float4*)(gw + e * 2048 + c0 + j8 * 8 + 4);
      acc[e] += xf[0] * g0.x + xf[1] * g0.y + xf[2] * g0.z + xf[3] * g0.w +
                xf[4] * g1.x + xf[5] * g1.y + xf[6] * g1.z + xf[7] * g1.w;
    }
  }
#pragma unroll
  for (int e = 0; e < 8; ++e) {
    acc[e] += __shfl_down(acc[e], 16);
    acc[e] += __shfl_down(acc[e], 32);
  }
  if (lane < 16) {
#pragma unroll
    for (int e = 0; e < 8; ++e) red[wave][lane][e] = acc[e];
  }
  __syncthreads();
  if (tid < 16) {
    float lg[8];
#pragma unroll
    for (int e = 0; e < 8; ++e)
      lg[e] = red[0][tid][e] + red[1][tid][e] + red[2][tid][e] + red[3][tid][e];
    int a = 0;
    for (int e = 1; e < 8; ++e) if (lg[e] > lg[a]) a = e;
    int b = (a == 0) ? 1 : 0;
    for (int e = 0; e < 8; ++e) if (e != a && lg[e] > lg[b]) b = e;
    const float d = __expf(lg[b] - lg[a]);
    float o[8] = {0, 0, 0, 0, 0, 0, 0, 0};
    o[a] = 1.0f / (1.0f + d);
    o[b] = d / (1.0f + d);
#pragma unroll
    for (int e = 0; e < 8; ++e) cws[tid][e] = o[e];
  }
  __syncthreads();

  // ---- phase 3: t = xs @ A2^T ----
  const int m = lane & 15, q = lane >> 4;
  const int nt0 = wave * 2;
  f32x4 tacc[2] = {};
  for (int ks = 0; ks < 64; ++ks) {
    bf16x8 af = *(const bf16x8*)&xs[m][ks * 32 + q * 8];
#pragma unroll
    for (int h = 0; h < 2; ++h) {
      bf16x8 bfg = *(const bf16x8*)(A2 + (size_t)((nt0 + h) * 16 + m) * 2048 +
                                    ks * 32 + q * 8);
      tacc[h] = __builtin_amdgcn_mfma_f32_16x16x32_bf16(af, bfg, tacc[h], 0, 0, 0);
    }
  }
#pragma unroll
  for (int h = 0; h < 2; ++h) {
    const int nt = nt0 + h;
#pragma unroll
    for (int rg = 0; rg < 4; ++rg) {
      const int trow = q * 4 + rg;
      const float s = tacc[h][rg] * 16.0f * cws[trow][nt];
      Abuf[(size_t)(t0 + trow) * 2176 + 2048 + nt * 16 + m] = f2bf(s);
    }
  }
}

// ---------------- ks-split deep-pipelined MFMA GEMM ----------------
// C[m,n] = sum_k A[m,k]*B[n,k].  BM=256, BN=128, BK=64. 512 threads = 8 waves.
// Waves 0-3: 2x2 grid of 128x64 output tiles, K-half ks=0 of each BK tile.
// Waves 4-7: same tiles, K-half ks=1. Partials combined via LDS at the end.
// Per wave per K-tile: 12 ds_read_b128 -> 32 MFMA (reuse 5.33x).
// 3 LDS buffers (144 KB), fine 2-phase interleave, counted vmcnt(6).
__global__ __launch_bounds__(512, 2) void mfma_gemm_bt3(
    const __bf16* __restrict__ A, const __bf16* __restrict__ B,
    float* __restrict__ C, int lda, int ldb, int ldc, int kiters) {
  __shared__ __align__(16) __bf16 lds[3 * 24576];  // 144 KB
  const int tid = threadIdx.x;
  const int wave = tid >> 6;
  const int lane = tid & 63;

  // XCD-aware swizzle: 8 XCDs as 4x2 grid of (4 M-tiles x 8 N-tiles) rectangles.
  const int wg = blockIdx.x + (blockIdx.y << 4);
  const int xcd = wg & 7, loc = wg >> 3;
  const int tm = ((xcd & 3) * 4 + (loc & 3)) * 256;
  const int tn = ((xcd >> 2) * 8 + (loc >> 2)) * 128;

  const int srow = lane >> 3;                 // row within 8-row staging chunk
  const int skoff = ((lane & 7) ^ srow) * 8;  // XOR-swizzled k offset (elems)

  const int wid = wave & 3;
  const int wr = wid >> 1, wc = wid & 1;      // 2x2 wave grid of 128x64 tiles
  const int ks4 = (wave >> 2) * 4;            // K-half: 0 or 4 (k-chunk units)
  const int rlo = lane & 7;
  const int rb3 = (lane >> 3) & 1;
  const int qb = lane >> 4;
  const int q8 = ((ks4 + qb) ^ rlo) * 8;      // swizzled k byte-group (const!)

  f32x4 acc[8][4] = {};

  // staging: 48 chunk-loads of [8 rows][64 k] split over 8 waves, 3+3 per thread
  auto stageA = [&](int buf, int kt) {
    const int kc = kt * 64;
    __bf16* Ls = lds + buf * 24576;
#pragma unroll
    for (int r = 0; r < 3; ++r) {
      const int ch = wave + r * 8;  // A chunks 0..23
      ld_lds16(A + (size_t)(tm + ch * 8 + srow) * lda + kc + skoff, &Ls[ch * 512]);
    }
  };
  auto stageB = [&](int buf, int kt) {
    const int kc = kt * 64;
    __bf16* Ls = lds + buf * 24576;
    const int ch = wave + 24;       // A chunks 24..31
    ld_lds16(A + (size_t)(tm + ch * 8 + srow) * lda + kc + skoff, &Ls[ch * 512]);
#pragma unroll
    for (int r = 0; r < 2; ++r) {
      const int bh = wave + r * 8;  // B chunks 0..15
      ld_lds16(B + (size_t)(tn + bh * 8 + srow) * ldb + kc + skoff,
               &Ls[16384 + bh * 512]);
    }
  };

  // prologue: tiles 0 and 1 in flight; tile 0 landed, tile 1's 6 stay in flight
  stageA(0, 0); stageB(0, 0);
  stageA(1, 1); stageB(1, 1);
  asm volatile("s_waitcnt vmcnt(6)" ::: "memory");
  __builtin_amdgcn_s_barrier();

  int cb = 0;
  for (int kt = 0; kt < kiters; ++kt) {
    const bool pf = (kt + 2 < kiters);
    const int nb = (kt + 2) % 3;
    const __bf16* As = lds + cb * 24576;
    const __bf16* Bs = As + 16384;

    // ---- phase A: B-frags + A-frags i=0..3, first staging half ----
    bf16x8 af[4], bfg[4];
#pragma unroll
    for (int j = 0; j < 4; ++j) {
      const int rh = wc * 8 + j * 2 + rb3;
      bfg[j] = *(const bf16x8*)&Bs[rh * 512 + rlo * 64 + q8];
    }
#pragma unroll
    for (int i = 0; i < 4; ++i) {
      const int rh = wr * 16 + i * 2 + rb3;
      af[i] = *(const bf16x8*)&As[rh * 512 + rlo * 64 + q8];
    }
    if (pf) stageA(nb, kt + 2);
    __builtin_amdgcn_s_barrier();
    asm volatile("s_waitcnt lgkmcnt(0)" ::: "memory");
    __builtin_amdgcn_s_setprio(1);
#pragma unroll
    for (int i = 0; i < 4; ++i)
#pragma unroll
      for (int j = 0; j < 4; ++j)
        acc[i][j] =
            __builtin_amdgcn_mfma_f32_16x16x32_bf16(af[i], bfg[j], acc[i][j], 0, 0, 0);
    __builtin_amdgcn_s_setprio(0);
    __builtin_amdgcn_s_barrier();

    // ---- phase B: A-frags i=4..7, second staging half, counted vmcnt ----
    bf16x8 ag[4];
#pragma unroll
    for (int i = 0; i < 4; ++i) {
      const int rh = wr * 16 + 8 + i * 2 + rb3;
      ag[i] = *(const bf16x8*)&As[rh * 512 + rlo * 64 + q8];
    }
    if (pf) {
      stageB(nb, kt + 2);
      asm volatile("s_waitcnt vmcnt(6)" ::: "memory");
    } else {
      asm volatile("s_waitcnt vmcnt(0)" ::: "memory");
    }
    __builtin_amdgcn_s_barrier();
    asm volatile("s_waitcnt lgkmcnt(0)" ::: "memory");
    __builtin_amdgcn_s_setprio(1);
#pragma unroll
    for (int i = 0; i < 4; ++i)
#pragma unroll
      for (int j = 0; j < 4; ++j)
        acc[4 + i][j] =
            __builtin_amdgcn_mfma_f32_16x16x32_bf16(ag[i], bfg[j], acc[4 + i][j], 0, 0, 0);
    __builtin_amdgcn_s_setprio(0);
    __builtin_amdgcn_s_barrier();
    cb = (cb + 1 == 3) ? 0 : cb + 1;
  }

  // ---- epilogue: combine the two K-halves via LDS, then store ----
  // layout: frag (i*4+j) -> 1024 floats = [wid 4][lane 64][4]; 16B/lane, no conflicts
  float* red = (float*)lds;
  if (wave >= 4) {
#pragma unroll
    for (int i = 0; i < 8; ++i)
#pragma unroll
      for (int j = 0; j < 4; ++j)
        *(f32x4*)&red[(i * 4 + j) * 1024 + wid * 256 + lane * 4] = acc[i][j];
  }
  __syncthreads();
  if (wave < 4) {
    const int crow0 = tm + wr * 128 + (lane >> 4) * 4;
    const int ccol0 = tn + wc * 64 + (lane & 15);
#pragma unroll
    for (int i = 0; i < 8; ++i)
#pragma unroll
      for (int j = 0; j < 4; ++j) {
        f32x4 v = acc[i][j] +
                  *(const f32x4*)&red[(i * 4 + j) * 1024 + wid * 256 + lane * 4];
#pragma unroll
        for (int rg = 0; rg < 4; ++rg)
          C[(size_t)(crow0 + i * 16 + rg) * ldc + ccol0 + j * 16] = v[rg];
      }
  }
}

extern "C" void kernel_launch(void* const* d_in, const int* in_sizes, int n_in,
                              void* d_out, int out_size, void* d_ws, size_t ws_size,
                              hipStream_t stream) {
  const float* x = (const float*)d_in[0];       // [2,2048,2048] -> [4096,2048]
  const float* weight = (const float*)d_in[1];  // [2048,2048]
  const float* gate_w = (const float*)d_in[2];  // [8,2048]
  const float* A_w = (const float*)d_in[3];     // [8,16,2048] == [128,2048]
  const float* B_w = (const float*)d_in[4];     // [8,2048,16]
  float* out = (float*)d_out;                   // [4096,2048]

  char* ws = (char*)d_ws;
  __bf16* Abuf = (__bf16*)ws;                // [4096,2176] bf16 = 17,825,792 B
  __bf16* Bfull = (__bf16*)(ws + 17825792);  // [2048,2176] bf16 =  8,912,896 B
  __bf16* A2 = (__bf16*)(ws + 26738688);     // [128,2048]  bf16 =    524,288 B

  // 1. prep: W -> Bfull[:,0:2048]; A_w -> A2; B_w -> Bfull[:,2048:2176]
  prep_kernel<<<2240, 256, 0, stream>>>(weight, A_w, B_w, Bfull, A2);
  // 2. router + x->bf16 + LoRA-down (t2) into Abuf
  router_t2<<<256, 256, 0, stream>>>(x, gate_w, A2, Abuf);
  // 3. out = Abuf @ Bfull^T  (K=2176 fuses base + LoRA-up)
  mfma_gemm_bt3<<<dim3(16, 16), 512, 0, stream>>>(Abuf, Bfull, out, 2176, 2176,
                                                  2048, 34);
}

// Round 3
// 159.710 us; speedup vs baseline: 1.0551x; 1.0188x over previous
//
#include <hip/hip_runtime.h>
#include <hip/hip_bf16.h>

// MoLoRA = base linear + top-2 routed LoRA.
//   Abuf[T,2176] = [ bf16(x) | bf16(alpha*cw*(x@A2^T)) ]      (A2 = A_w as [128,2048])
//   Bfull[O,2176] = [ bf16(W) | bf16(B2^T) ]   (B2[e*16+r,o]=B_w[e,o,r])
//   out[T,O] = Abuf @ Bfull^T     -- single bf16 MFMA GEMM, K=2176
// T=4096, H=2048, O=2048, E=8, R=16, Kaug=2176.
//
// R1: XOR k-chunk LDS swizzle -> SQ_LDS_BANK_CONFLICT 1.34e7 -> 0.
// R2: 128x64 tiles / fused router (3 dispatches total).
// R3: 256x128 mega-block, 8 waves, 3-deep pipeline: 45.8us, Mfma 30%.
// R4: ks-split + fine 2-phase: 46.8us, Mfma 30.6% -- schedule micro-structure
//     is NOT the limiter; every 1-block/CU lockstep config lands ~30%.
// R5: (a) GEMM -> 128x128, 4 waves (64x64/wave), BK=64, 2-buf 64KB LDS,
//         grid 512 = 2 CO-RESIDENT blocks/CU: two independent barrier groups
//         per CU so one block's MFMAs cover the other's stage/barrier stalls
//         (m114 co-schedule; m97 precedent: simple 2-barrier 128^2 loop at
//         3 blocks/CU = 37% MfmaUtil). Counted vmcnt(8), setprio, XCD chunks.
//     (b) prep/router: manual 4-op RNE f2bf -> native cast (compiler emits
//         v_cvt_pk_bf16_f32, same RNE, 2 elems/instr) -- halves cvt VALU.

typedef __bf16 bf16x8 __attribute__((ext_vector_type(8)));
typedef float f32x4 __attribute__((ext_vector_type(4)));

__device__ __forceinline__ __bf16 f2bf(float f) { return (__bf16)f; }  // RNE via v_cvt_pk_bf16_f32

__device__ __forceinline__ void ld_lds16(const void* g, void* l) {
  __builtin_amdgcn_global_load_lds((__attribute__((address_space(1))) void*)g,
                                   (__attribute__((address_space(3))) void*)l,
                                   16, 0, 0);
}

// ---------------- fused prep: W->Bfull[:,0:2048], A_w->A2, B_w->Bfull[:,2048:] ----
__global__ void prep_kernel(const float* __restrict__ W, const float* __restrict__ Aw,
                            const float* __restrict__ Bw, __bf16* __restrict__ Bfull,
                            __bf16* __restrict__ A2) {
  const int b = blockIdx.x, tid = threadIdx.x;
  if (b < 2176) {
    const float* src = (b < 2048) ? (W + (size_t)b * 2048)
                                  : (Aw + (size_t)(b - 2048) * 2048);
    __bf16* dst = (b < 2048) ? (Bfull + (size_t)b * 2176)
                             : (A2 + (size_t)(b - 2048) * 2048);
    const int c = tid * 8;
    float4 a = *(const float4*)(src + c);
    float4 d = *(const float4*)(src + c + 4);
    bf16x8 v;
    v[0] = f2bf(a.x); v[1] = f2bf(a.y); v[2] = f2bf(a.z); v[3] = f2bf(a.w);
    v[4] = f2bf(d.x); v[5] = f2bf(d.y); v[6] = f2bf(d.z); v[7] = f2bf(d.w);
    *(bf16x8*)(dst + c) = v;
  } else {
    // pack B_w [E,O,R] -> Bfull[o, 2048 + e*16 + r]
    const int idx = (b - 2176) * 256 + tid;  // 0..16383
    const int e = idx >> 11, o = idx & 2047;
    const float4* s = (const float4*)(Bw + ((size_t)e * 2048 + o) * 16);
    float4 v0 = s[0], v1 = s[1], v2 = s[2], v3 = s[3];
    __bf16* d = Bfull + (size_t)o * 2176 + 2048 + e * 16;
    bf16x8 lo, hi;
    lo[0] = f2bf(v0.x); lo[1] = f2bf(v0.y); lo[2] = f2bf(v0.z); lo[3] = f2bf(v0.w);
    lo[4] = f2bf(v1.x); lo[5] = f2bf(v1.y); lo[6] = f2bf(v1.z); lo[7] = f2bf(v1.w);
    hi[0] = f2bf(v2.x); hi[1] = f2bf(v2.y); hi[2] = f2bf(v2.z); hi[3] = f2bf(v2.w);
    hi[4] = f2bf(v3.x); hi[5] = f2bf(v3.y); hi[6] = f2bf(v3.z); hi[7] = f2bf(v3.w);
    *(bf16x8*)d = lo;
    *(bf16x8*)(d + 8) = hi;
  }
}

// ---------------- fused router + LoRA-down (t2) ----------------
__global__ __launch_bounds__(256) void router_t2(
    const float* __restrict__ x, const float* __restrict__ gw,
    const __bf16* __restrict__ A2, __bf16* __restrict__ Abuf) {
  __shared__ __align__(16) __bf16 xs[16][2056];  // 64.25 KB, +8 pad
  __shared__ float red[4][16][8];
  __shared__ float cws[16][8];
  const int tid = threadIdx.x;
  const int wave = tid >> 6, lane = tid & 63;
  const int t0 = blockIdx.x * 16;

  // ---- phase 1: one token-row per iteration, fully coalesced ----
#pragma unroll 4
  for (int i = 0; i < 16; ++i) {
    const float* xr = x + (size_t)(t0 + i) * 2048 + tid * 8;
    float4 a = *(const float4*)xr;
    float4 b = *(const float4*)(xr + 4);
    bf16x8 v;
    v[0] = f2bf(a.x); v[1] = f2bf(a.y); v[2] = f2bf(a.z); v[3] = f2bf(a.w);
    v[4] = f2bf(b.x); v[5] = f2bf(b.y); v[6] = f2bf(b.z); v[7] = f2bf(b.w);
    *(bf16x8*)(Abuf + (size_t)(t0 + i) * 2176 + tid * 8) = v;
    *(bf16x8*)&xs[i][tid * 8] = v;
  }
  __syncthreads();

  // ---- phase 2: logits ----
  const int tok = tid & 15, slc = tid >> 4;
  const int c0 = slc * 128;
  float acc[8] = {0, 0, 0, 0, 0, 0, 0, 0};
  for (int j8 = 0; j8 < 16; ++j8) {
    bf16x8 xv = *(const bf16x8*)&xs[tok][c0 + j8 * 8];
    float xf[8];
#pragma unroll
    for (int j = 0; j < 8; ++j) xf[j] = (float)xv[j];
#pragma unroll
    for (int e = 0; e < 8; ++e) {
      float4 g0 = *(const float4*)(gw + e * 2048 + c0 + j8 * 8);
      float4 g1 = *(const float4*)(gw + e * 2048 + c0 + j8 * 8 + 4);
      acc[e] += xf[0] * g0.x + xf[1] * g0.y + xf[2] * g0.z + xf[3] * g0.w +
                xf[4] * g1.x + xf[5] * g1.y + xf[6] * g1.z + xf[7] * g1.w;
    }
  }
#pragma unroll
  for (int e = 0; e < 8; ++e) {
    acc[e] += __shfl_down(acc[e], 16);
    acc[e] += __shfl_down(acc[e], 32);
  }
  if (lane < 16) {
#pragma unroll
    for (int e = 0; e < 8; ++e) red[wave][lane][e] = acc[e];
  }
  __syncthreads();
  if (tid < 16) {
    float lg[8];
#pragma unroll
    for (int e = 0; e < 8; ++e)
      lg[e] = red[0][tid][e] + red[1][tid][e] + red[2][tid][e] + red[3][tid][e];
    int a = 0;
    for (int e = 1; e < 8; ++e) if (lg[e] > lg[a]) a = e;
    int b = (a == 0) ? 1 : 0;
    for (int e = 0; e < 8; ++e) if (e != a && lg[e] > lg[b]) b = e;
    const float d = __expf(lg[b] - lg[a]);
    float o[8] = {0, 0, 0, 0, 0, 0, 0, 0};
    o[a] = 1.0f / (1.0f + d);
    o[b] = d / (1.0f + d);
#pragma unroll
    for (int e = 0; e < 8; ++e) cws[tid][e] = o[e];
  }
  __syncthreads();

  // ---- phase 3: t = xs @ A2^T ----
  const int m = lane & 15, q = lane >> 4;
  const int nt0 = wave * 2;
  f32x4 tacc[2] = {};
  for (int ks = 0; ks < 64; ++ks) {
    bf16x8 af = *(const bf16x8*)&xs[m][ks * 32 + q * 8];
#pragma unroll
    for (int h = 0; h < 2; ++h) {
      bf16x8 bfg = *(const bf16x8*)(A2 + (size_t)((nt0 + h) * 16 + m) * 2048 +
                                    ks * 32 + q * 8);
      tacc[h] = __builtin_amdgcn_mfma_f32_16x16x32_bf16(af, bfg, tacc[h], 0, 0, 0);
    }
  }
#pragma unroll
  for (int h = 0; h < 2; ++h) {
    const int nt = nt0 + h;
#pragma unroll
    for (int rg = 0; rg < 4; ++rg) {
      const int trow = q * 4 + rg;
      const float s = tacc[h][rg] * 16.0f * cws[trow][nt];
      Abuf[(size_t)(t0 + trow) * 2176 + 2048 + nt * 16 + m] = f2bf(s);
    }
  }
}

// ---------------- multi-block MFMA GEMM: C[m,n] = sum_k A[m,k]*B[n,k] ----------
// 128x128 tile, BK=64, 256 threads = 4 waves (2x2 of 64x64). LDS: 2 buffers x
// (A 16KB + B 16KB) = 64KB -> 2 blocks/CU co-resident (independent barrier
// groups; cross-block slip hides stage/barrier stalls). Grid 32x16 = 512 blocks
// = exactly 2/CU. Counted vmcnt(8): next tile's 8 gloads stay in flight across
// the barrier; this tile's 8 are guaranteed landed. XOR k-chunk swizzle as R1.
__global__ __launch_bounds__(256, 2) void mfma_gemm_bt4(
    const __bf16* __restrict__ A, const __bf16* __restrict__ B,
    float* __restrict__ C, int lda, int ldb, int ldc, int kiters) {
  __shared__ __align__(16) __bf16 lds[2 * 16384];  // 64 KB: [buf][A 8192 | B 8192]
  const int tid = threadIdx.x;
  const int wave = tid >> 6;
  const int lane = tid & 63;

  // XCD chunking: 512 wgs, 8 XCDs -> 64 consecutive ids per XCD, shaped 8Mx8N.
  const int wg = blockIdx.x + (blockIdx.y << 5);  // 32 M-tiles x 16 N-tiles
  const int xcd = wg & 7, loc = wg >> 3;          // loc 0..63
  const int tm = ((xcd & 3) * 8 + (loc >> 3)) * 128;
  const int tn = ((xcd >> 2) * 8 + (loc & 7)) * 128;

  const int srow = lane >> 3;                 // row within 8-row staging chunk
  const int skoff = ((lane & 7) ^ srow) * 8;  // XOR-swizzled k offset (elems)

  const int wr = wave >> 1, wc = wave & 1;    // 2x2 wave grid of 64x64 tiles
  const int rlo = lane & 7;
  const int rb3 = (lane >> 3) & 1;
  const int qb = lane >> 4;

  f32x4 acc[4][4] = {};

  // stage tile kt into buffer buf: 32 chunks ([8 rows][64 k] each), 8/wave
  auto stage = [&](int buf, int kt) {
    const int kc = kt * 64;
    __bf16* Ls = lds + buf * 16384;
#pragma unroll
    for (int r = 0; r < 4; ++r) {
      const int ch = wave + r * 4;  // A chunks 0..15 (rows tm..tm+127)
      ld_lds16(A + (size_t)(tm + ch * 8 + srow) * lda + kc + skoff, &Ls[ch * 512]);
    }
#pragma unroll
    for (int r = 0; r < 4; ++r) {
      const int ch = wave + r * 4;  // B chunks 0..15 (rows tn..tn+127)
      ld_lds16(B + (size_t)(tn + ch * 8 + srow) * ldb + kc + skoff,
               &Ls[8192 + ch * 512]);
    }
  };

  stage(0, 0);  // prologue: tile 0 in flight

  for (int kt = 0; kt < kiters; ++kt) {
    const int cb = kt & 1;
    if (kt + 1 < kiters) {
      stage(cb ^ 1, kt + 1);  // overwrites buffer read at kt-1 (barrier-safe)
      asm volatile("s_waitcnt vmcnt(8)" ::: "memory");  // tile kt landed
    } else {
      asm volatile("s_waitcnt vmcnt(0)" ::: "memory");
    }
    __builtin_amdgcn_s_barrier();

    const __bf16* As = lds + cb * 16384;
    const __bf16* Bs = As + 8192;
#pragma unroll
    for (int ks = 0; ks < 2; ++ks) {
      bf16x8 af[4], bfg[4];
      const int q8 = ((ks * 4 + qb) ^ rlo) * 8;
#pragma unroll
      for (int i = 0; i < 4; ++i) {
        const int rh = wr * 8 + i * 2 + rb3;
        af[i] = *(const bf16x8*)&As[rh * 512 + rlo * 64 + q8];
      }
#pragma unroll
      for (int j = 0; j < 4; ++j) {
        const int rh = wc * 8 + j * 2 + rb3;
        bfg[j] = *(const bf16x8*)&Bs[rh * 512 + rlo * 64 + q8];
      }
      __builtin_amdgcn_s_setprio(1);
#pragma unroll
      for (int i = 0; i < 4; ++i)
#pragma unroll
        for (int j = 0; j < 4; ++j)
          acc[i][j] =
              __builtin_amdgcn_mfma_f32_16x16x32_bf16(af[i], bfg[j], acc[i][j], 0, 0, 0);
      __builtin_amdgcn_s_setprio(0);
    }
    __builtin_amdgcn_s_barrier();  // all reads of buf cb done before next overwrite
  }

  // C/D layout: col = lane&15, row = (lane>>4)*4 + reg
  const int crow0 = tm + wr * 64 + (lane >> 4) * 4;
  const int ccol0 = tn + wc * 64 + (lane & 15);
#pragma unroll
  for (int i = 0; i < 4; ++i)
#pragma unroll
    for (int j = 0; j < 4; ++j)
#pragma unroll
      for (int rg = 0; rg < 4; ++rg)
        C[(size_t)(crow0 + i * 16 + rg) * ldc + ccol0 + j * 16] = acc[i][j][rg];
}

extern "C" void kernel_launch(void* const* d_in, const int* in_sizes, int n_in,
                              void* d_out, int out_size, void* d_ws, size_t ws_size,
                              hipStream_t stream) {
  const float* x = (const float*)d_in[0];       // [2,2048,2048] -> [4096,2048]
  const float* weight = (const float*)d_in[1];  // [2048,2048]
  const float* gate_w = (const float*)d_in[2];  // [8,2048]
  const float* A_w = (const float*)d_in[3];     // [8,16,2048] == [128,2048]
  const float* B_w = (const float*)d_in[4];     // [8,2048,16]
  float* out = (float*)d_out;                   // [4096,2048]

  char* ws = (char*)d_ws;
  __bf16* Abuf = (__bf16*)ws;                // [4096,2176] bf16 = 17,825,792 B
  __bf16* Bfull = (__bf16*)(ws + 17825792);  // [2048,2176] bf16 =  8,912,896 B
  __bf16* A2 = (__bf16*)(ws + 26738688);     // [128,2048]  bf16 =    524,288 B

  // 1. prep: W -> Bfull[:,0:2048]; A_w -> A2; B_w -> Bfull[:,2048:2176]
  prep_kernel<<<2240, 256, 0, stream>>>(weight, A_w, B_w, Bfull, A2);
  // 2. router + x->bf16 + LoRA-down (t2) into Abuf
  router_t2<<<256, 256, 0, stream>>>(x, gate_w, A2, Abuf);
  // 3. out = Abuf @ Bfull^T  (K=2176 fuses base + LoRA-up)
  mfma_gemm_bt4<<<dim3(32, 16), 256, 0, stream>>>(Abuf, Bfull, out, 2176, 2176,
                                                  2048, 34);
}